// Round 4
// baseline (2399.126 us; speedup 1.0000x reference)
//
#include <hip/hip_runtime.h>
#include <math.h>

#define TPB 1024

typedef __attribute__((ext_vector_type(8))) short bf16x8;
typedef __attribute__((ext_vector_type(4))) float f32x4;
typedef unsigned short u16;

#define MFMA(a, b, c) __builtin_amdgcn_mfma_f32_16x16x32_bf16(a, b, c, 0, 0, 0)

__device__ __forceinline__ u16 f2bf(float f) {
  union { float f; unsigned u; } v; v.f = f;
  unsigned u = v.u;
  return (u16)((u + 0x7fffu + ((u >> 16) & 1u)) >> 16);  // RNE
}
__device__ __forceinline__ float bf2f(u16 h) {
  union { unsigned u; float f; } v; v.u = ((unsigned)h) << 16; return v.f;
}

// fragment from LDS bf16 [row][pitch]: lane row = row0+(lane&15), k = kb+(lane>>4)*8+j
__device__ __forceinline__ bf16x8 fragL(const u16* B, int row0, int pitch, int kb, int lane) {
  return *(const bf16x8*)(B + (row0 + (lane & 15)) * pitch + kb + ((lane >> 4) << 3));
}
// fragment from global fp32 [row][stride] with on-the-fly bf16 convert (PREW=0 fallback)
__device__ __forceinline__ bf16x8 fragG(const float* __restrict__ W, int row0, int stride,
                                        int kb, int lane) {
  const float* p = W + (size_t)(row0 + (lane & 15)) * stride + kb + ((lane >> 4) << 3);
  float4 a = *(const float4*)p, b = *(const float4*)(p + 4);
  bf16x8 r;
  r[0] = (short)f2bf(a.x); r[1] = (short)f2bf(a.y); r[2] = (short)f2bf(a.z); r[3] = (short)f2bf(a.w);
  r[4] = (short)f2bf(b.x); r[5] = (short)f2bf(b.y); r[6] = (short)f2bf(b.z); r[7] = (short)f2bf(b.w);
  return r;
}

// encoder weight fragment: pre-swizzled bf16 in ws (PREW=1) or fp32 global (PREW=0)
template<int PREW>
__device__ __forceinline__ bf16x8 wfrag(const float* __restrict__ Wg,
                                        const u16* __restrict__ Wp,
                                        int m, int f, int kh, int lane) {
  if constexpr (PREW)
    return *(const bf16x8*)(Wp + (size_t)m * 4096 + f * 1024 + kh * 512 + lane * 8);
  else
    return fragG(Wg, f * 16, 64, kh * 32, lane);
}

// matmul + bias + residual + LayerNorm (4-way cross-wave partials); caller barriers after
template<int PREW>
__device__ __forceinline__ void mmLN16(const u16* __restrict__ src,
                                       const float* __restrict__ Wg,
                                       const u16* __restrict__ Wp, int m,
                                       const float* __restrict__ bias,
                                       const float* __restrict__ g,
                                       const float* __restrict__ be,
                                       u16* __restrict__ ysB, float* __restrict__ red,
                                       int m0, int wc, int lane) {
  const int lx = lane & 15;
  const int col = wc * 16 + lx;
  bf16x8 a0 = fragL(src, m0, 72, 0, lane);
  bf16x8 a1 = fragL(src, m0, 72, 32, lane);
  f32x4 acc = {0.f, 0.f, 0.f, 0.f};
  acc = MFMA(a0, wfrag<PREW>(Wg, Wp, m, wc, 0, lane), acc);
  acc = MFMA(a1, wfrag<PREW>(Wg, Wp, m, wc, 1, lane), acc);
  float bv = bias[col];
  float t[4];
#pragma unroll
  for (int j = 0; j < 4; ++j) {
    int row = m0 + ((lane >> 4) << 2) + j;
    t[j] = acc[j] + bv + bf2f(ysB[row * 72 + col]);
  }
#pragma unroll
  for (int j = 0; j < 4; ++j) {
    float s1 = t[j], s2 = t[j] * t[j];
    s1 += __shfl_xor(s1, 1); s2 += __shfl_xor(s2, 1);
    s1 += __shfl_xor(s1, 2); s2 += __shfl_xor(s2, 2);
    s1 += __shfl_xor(s1, 4); s2 += __shfl_xor(s2, 4);
    s1 += __shfl_xor(s1, 8); s2 += __shfl_xor(s2, 8);
    if (lx == 0) {
      int row = m0 + ((lane >> 4) << 2) + j;
      red[(wc * 64 + row) * 2 + 0] = s1;
      red[(wc * 64 + row) * 2 + 1] = s2;
    }
  }
  __syncthreads();
#pragma unroll
  for (int j = 0; j < 4; ++j) {
    int row = m0 + ((lane >> 4) << 2) + j;
    float s1 = red[row * 2] + red[(64 + row) * 2] + red[(128 + row) * 2] + red[(192 + row) * 2];
    float s2 = red[row * 2 + 1] + red[(64 + row) * 2 + 1] + red[(128 + row) * 2 + 1] + red[(192 + row) * 2 + 1];
    float mu = s1 * 0.015625f;
    float rstd = rsqrtf(s2 * 0.015625f - mu * mu + 1e-5f);
    ysB[row * 72 + col] = f2bf((t[j] - mu) * rstd * g[col] + be[col]);
  }
}

// pre-swizzle 12 encoder 64x64 matrices into bf16 fragment layout
__global__ __launch_bounds__(256)
void prep_kernel(const float* __restrict__ t_inw, const float* __restrict__ t_ow,
                 const float* __restrict__ t_w1, const float* __restrict__ t_w2,
                 u16* __restrict__ wp) {
  int m = blockIdx.x;            // 0..11 = layer*6 + {Wq,Wk,Wv,ow,w1,w2}
  int l = m / 6, r = m % 6;
  const float* W;
  if (r < 3)      W = t_inw + l * 12288 + r * 4096;
  else if (r == 3) W = t_ow + l * 4096;
  else if (r == 4) W = t_w1 + l * 4096;
  else             W = t_w2 + l * 4096;
  for (int t = threadIdx.x; t < 4096; t += 256) {
    int j = t & 7, ln = (t >> 3) & 63, kh = (t >> 9) & 1, f = t >> 10;
    int row = f * 16 + (ln & 15);
    int k = kh * 32 + ((ln >> 4) << 3) + j;
    wp[(size_t)m * 4096 + t] = f2bf(W[row * 64 + k]);
  }
}

template<int PREW>
__global__ __launch_bounds__(TPB)
void gcrnn_kernel(const float* __restrict__ x,      // (128,3,64,96)
                  const float* __restrict__ adj,    // (64,64)
                  const float* __restrict__ h0,     // (128,64,64)
                  const float* __restrict__ t_inw, const float* __restrict__ t_inb,
                  const float* __restrict__ t_ow,  const float* __restrict__ t_ob,
                  const float* __restrict__ t_w1,  const float* __restrict__ t_b1,
                  const float* __restrict__ t_w2,  const float* __restrict__ t_b2,
                  const float* __restrict__ t_g1,  const float* __restrict__ t_be1,
                  const float* __restrict__ t_g2,  const float* __restrict__ t_be2,
                  const float* __restrict__ uw,    const float* __restrict__ ub,
                  const float* __restrict__ cw,    const float* __restrict__ cb,
                  const u16* __restrict__ wsW,     // pre-swizzled encoder weights (PREW)
                  float* __restrict__ wsOut,       // staging [b][s][d][n] (if useStage)
                  float* __restrict__ out,         // (128,64,64,96)
                  int useStage)
{
  const int b = blockIdx.x;
  const int tid = threadIdx.x;
  const int wv = tid >> 6;          // 0..15
  const int lane = tid & 63;
  const int lx = lane & 15;
  const int gq = (lane >> 4) << 2;  // row offset within 16-row tile: 0,4,8,12
  const int wr = wv & 3, wc = wv >> 2;
  const int m0 = wr * 16;           // row stripe
  const int col = wc * 16 + lx;     // column owned in 64-col outputs

  __shared__ __align__(16) u16 adjB[64 * 72];          //  9216 B adj[w][v]
  __shared__ __align__(16) u16 ysB[64 * 72];           //  9216 B y[n][d] / h^T
  __shared__ __align__(16) float red[4 * 64 * 2];      //  2048 B cross-wave partials
  __shared__ __align__(16) u16 pool[18432];            // 36864 B Qb|Kb|VTb|Pb / xgB|x1B
  __shared__ __align__(16) u16 zTB[64 * 232];          // 29696 B zT[n][c], c 204..231 = 0
  __shared__ __align__(16) u16 uwcwB[2 * 4 * 7 * 512]; // 57344 B conv weight frags
  // total 144384 B

  u16* Qb  = pool;
  u16* Kb  = pool + 4608;
  u16* VTb = pool + 9216;
  u16* Pb  = pool + 13824;
  u16* xgB = pool;          // 80 rows x 72 (rows >=68 alias Kb: garbage -> discarded cols)
  u16* x1B = pool + 5760;   // 80 rows x 72

  // ---- one-time init ----
  float hreg[4];   // h[o][n] tile: o = col, n = m0+gq+j
  {
    float4 hv = *(const float4*)(h0 + (size_t)b * 4096 + col * 64 + m0 + gq);
    hreg[0] = hv.x; hreg[1] = hv.y; hreg[2] = hv.z; hreg[3] = hv.w;
#pragma unroll
    for (int j = 0; j < 4; ++j)
      ysB[(m0 + gq + j) * 72 + col] = f2bf(hreg[j]);
  }
  for (int i = tid; i < 4096; i += TPB)
    adjB[(i >> 6) * 72 + (i & 63)] = f2bf(adj[i]);
  for (int i = tid; i < 2 * 4 * 7 * 512; i += TPB) {
    int t = i;
    int j = t & 7; t >>= 3;
    int ln = t & 63; t >>= 6;
    int kh = t % 7; t /= 7;
    int f = t & 3; int mat = t >> 2;
    int o = f * 16 + (ln & 15);
    int k = kh * 32 + ((ln >> 4) << 3) + j;
    const float* W = mat ? cw : uw;
    uwcwB[i] = (k < 204) ? f2bf(W[o * 204 + k]) : (u16)0;
  }
  for (int i = tid; i < 64 * 28; i += TPB)
    zTB[(i / 28) * 232 + 204 + (i % 28)] = 0;
  __syncthreads();

  const float* times = x + ((size_t)b * 3 + 2) * 64 * 96;  // x[b,2,0,:]
  float hdreg[4];

  for (int s = 0; s < 96; ++s) {
    float dcur = (s == 0) ? 0.f : (times[s] - times[s - 1]);
    float sq1 = sqrtf(1.f - dcur), sq2 = sqrtf(dcur);

    // ---- two encoder layers ----
    for (int l = 0; l < 2; ++l) {
      const int l6 = l * 6;
      const float* inw = t_inw + l * 12288;
      const float* inb = t_inb + l * 192;
      const float* ow  = t_ow  + l * 4096;
      const float* ob  = t_ob  + l * 64;
      const float* w1  = t_w1  + l * 4096;
      const float* bb1 = t_b1  + l * 64;
      const float* w2  = t_w2  + l * 4096;
      const float* bb2 = t_b2  + l * 64;
      const float* g1  = t_g1  + l * 64;
      const float* be1 = t_be1 + l * 64;
      const float* g2  = t_g2  + l * 64;
      const float* be2 = t_be2 + l * 64;

      // A: Q, K, V^T
      {
        bf16x8 ya0 = fragL(ysB, m0, 72, 0, lane);
        bf16x8 ya1 = fragL(ysB, m0, 72, 32, lane);
        {
          f32x4 acc = {0.f, 0.f, 0.f, 0.f};
          acc = MFMA(ya0, wfrag<PREW>(inw, wsW, l6 + 0, wc, 0, lane), acc);
          acc = MFMA(ya1, wfrag<PREW>(inw, wsW, l6 + 0, wc, 1, lane), acc);
          float bv = inb[col];
#pragma unroll
          for (int j = 0; j < 4; ++j)
            Qb[(m0 + gq + j) * 72 + col] = f2bf(acc[j] + bv);
        }
        {
          f32x4 acc = {0.f, 0.f, 0.f, 0.f};
          acc = MFMA(ya0, wfrag<PREW>(inw + 4096, wsW, l6 + 1, wc, 0, lane), acc);
          acc = MFMA(ya1, wfrag<PREW>(inw + 4096, wsW, l6 + 1, wc, 1, lane), acc);
          float bv = inb[64 + col];
#pragma unroll
          for (int j = 0; j < 4; ++j)
            Kb[(m0 + gq + j) * 72 + col] = f2bf(acc[j] + bv);
        }
        {
          // VT[dd][n] = Wv[dd,:]·y[n,:] : A = Wv rows (wr stripe), B = ysB rows (wc frag)
          f32x4 acc = {0.f, 0.f, 0.f, 0.f};
          acc = MFMA(wfrag<PREW>(inw + 8192, wsW, l6 + 2, wr, 0, lane),
                     fragL(ysB, wc * 16, 72, 0, lane), acc);
          acc = MFMA(wfrag<PREW>(inw + 8192, wsW, l6 + 2, wr, 1, lane),
                     fragL(ysB, wc * 16, 72, 32, lane), acc);
#pragma unroll
          for (int j = 0; j < 4; ++j) {
            int dd = m0 + gq + j;
            VTb[dd * 72 + col] = f2bf(acc[j] + inb[128 + dd]);
          }
        }
      }
      __syncthreads();

      // B: scores + softmax
      {
        f32x4 sc;
        {
          f32x4 acc = {0.f, 0.f, 0.f, 0.f};
          acc = MFMA(fragL(Qb, m0, 72, 0, lane), fragL(Kb, wc * 16, 72, 0, lane), acc);
          acc = MFMA(fragL(Qb, m0, 72, 32, lane), fragL(Kb, wc * 16, 72, 32, lane), acc);
#pragma unroll
          for (int j = 0; j < 4; ++j) acc[j] *= 0.125f;
          sc = acc;
        }
        float mw[4];
#pragma unroll
        for (int j = 0; j < 4; ++j) {
          float m1 = sc[j];
          m1 = fmaxf(m1, __shfl_xor(m1, 1));
          m1 = fmaxf(m1, __shfl_xor(m1, 2));
          m1 = fmaxf(m1, __shfl_xor(m1, 4));
          m1 = fmaxf(m1, __shfl_xor(m1, 8));
          float e = __expf(sc[j] - m1);
          sc[j] = e;
          float s1 = e;
          s1 += __shfl_xor(s1, 1); s1 += __shfl_xor(s1, 2);
          s1 += __shfl_xor(s1, 4); s1 += __shfl_xor(s1, 8);
          mw[j] = m1;
          if (lx == 0) {
            int row = m0 + gq + j;
            red[(wc * 64 + row) * 2 + 0] = m1;
            red[(wc * 64 + row) * 2 + 1] = s1;
          }
        }
        __syncthreads();
#pragma unroll
        for (int j = 0; j < 4; ++j) {
          int row = m0 + gq + j;
          float m0r = red[row * 2], m1r = red[(64 + row) * 2],
                m2r = red[(128 + row) * 2], m3r = red[(192 + row) * 2];
          float mm = fmaxf(fmaxf(m0r, m1r), fmaxf(m2r, m3r));
          float ss = red[row * 2 + 1] * __expf(m0r - mm)
                   + red[(64 + row) * 2 + 1] * __expf(m1r - mm)
                   + red[(128 + row) * 2 + 1] * __expf(m2r - mm)
                   + red[(192 + row) * 2 + 1] * __expf(m3r - mm);
          float scl = __expf(mw[j] - mm) / ss;
          Pb[row * 72 + col] = f2bf(sc[j] * scl);
        }
      }
      __syncthreads();

      // C: AO = P @ V -> Qb
      {
        f32x4 acc = {0.f, 0.f, 0.f, 0.f};
        acc = MFMA(fragL(Pb, m0, 72, 0, lane), fragL(VTb, wc * 16, 72, 0, lane), acc);
        acc = MFMA(fragL(Pb, m0, 72, 32, lane), fragL(VTb, wc * 16, 72, 32, lane), acc);
#pragma unroll
        for (int j = 0; j < 4; ++j)
          Qb[(m0 + gq + j) * 72 + col] = f2bf(acc[j]);
      }
      __syncthreads();

      // D: proj + residual + LN
      mmLN16<PREW>(Qb, ow, wsW, l6 + 3, ob, g1, be1, ysB, red, m0, wc, lane);
      __syncthreads();

      // E: FF1 relu -> Kb
      {
        f32x4 acc = {0.f, 0.f, 0.f, 0.f};
        acc = MFMA(fragL(ysB, m0, 72, 0, lane), wfrag<PREW>(w1, wsW, l6 + 4, wc, 0, lane), acc);
        acc = MFMA(fragL(ysB, m0, 72, 32, lane), wfrag<PREW>(w1, wsW, l6 + 4, wc, 1, lane), acc);
        float bv = bb1[col];
#pragma unroll
        for (int j = 0; j < 4; ++j)
          Kb[(m0 + gq + j) * 72 + col] = f2bf(fmaxf(acc[j] + bv, 0.f));
      }
      __syncthreads();

      // F: FF2 + residual + LN
      mmLN16<PREW>(Kb, w2, wsW, l6 + 5, bb2, g2, be2, ysB, red, m0, wc, lane);
      __syncthreads();
    }

    // G: xg[c][v] rows 0..67, zT cols 0..67, hd from registers
    {
      for (int i = tid; i < 256; i += TPB) {
        int f = i >> 6, n = i & 63;
        float v = (f < 3) ? x[(((size_t)b * 3 + f) * 64 + n) * 96 + s] : dcur;
        xgB[f * 72 + n] = f2bf(v);
        zTB[n * 232 + f] = f2bf(v);
      }
      // this lane's h tile: o = col, n = m0+gq+j; eps = y^T from ysB
      short4 hd4;
#pragma unroll
      for (int j = 0; j < 4; ++j) {
        int n = m0 + gq + j;
        float eps = bf2f(ysB[n * 72 + col]);
        float hd = sq1 * hreg[j] - sq2 * eps;
        hdreg[j] = hd;
        u16 hb = f2bf(hd);
        ((u16*)&hd4)[j] = hb;
        zTB[n * 232 + 4 + col] = hb;
      }
      *(short4*)(xgB + (4 + col) * 72 + m0 + gq) = hd4;  // 4 consecutive n
    }
    __syncthreads();

    // H: x1 = xg @ adjT (20 tiles) and x1T -> zT[68..135] (20 tiles)
    for (int t = wv; t < 40; t += 16) {
      if (t < 20) {
        int st = t >> 2, fq = t & 3;
        f32x4 acc = {0.f, 0.f, 0.f, 0.f};
        acc = MFMA(fragL(xgB, st * 16, 72, 0, lane), fragL(adjB, fq * 16, 72, 0, lane), acc);
        acc = MFMA(fragL(xgB, st * 16, 72, 32, lane), fragL(adjB, fq * 16, 72, 32, lane), acc);
#pragma unroll
        for (int j = 0; j < 4; ++j)
          x1B[(st * 16 + gq + j) * 72 + fq * 16 + lx] = f2bf(acc[j]);
      } else {
        int tt = t - 20;
        int rs = tt & 3, cf = tt >> 2;
        f32x4 acc = {0.f, 0.f, 0.f, 0.f};
        acc = MFMA(fragL(adjB, rs * 16, 72, 0, lane), fragL(xgB, cf * 16, 72, 0, lane), acc);
        acc = MFMA(fragL(adjB, rs * 16, 72, 32, lane), fragL(xgB, cf * 16, 72, 32, lane), acc);
        int c = cf * 16 + lx;
        if (c < 68) {
#pragma unroll
          for (int j = 0; j < 4; ++j)
            zTB[(rs * 16 + gq + j) * 232 + 68 + c] = f2bf(acc[j]);
        }
      }
    }
    __syncthreads();

    // I: x2T -> zT[136..203] (20 tiles)
    for (int t = wv; t < 20; t += 16) {
      int rs = t & 3, cf = t >> 2;
      f32x4 acc = {0.f, 0.f, 0.f, 0.f};
      acc = MFMA(fragL(adjB, rs * 16, 72, 0, lane), fragL(x1B, cf * 16, 72, 0, lane), acc);
      acc = MFMA(fragL(adjB, rs * 16, 72, 32, lane), fragL(x1B, cf * 16, 72, 32, lane), acc);
      int c = cf * 16 + lx;
      if (c < 68) {
#pragma unroll
        for (int j = 0; j < 4; ++j)
          zTB[(rs * 16 + gq + j) * 232 + 136 + c] = f2bf(acc[j]);
      }
    }
    __syncthreads();

    // J: conv (u,c) + gate -> hreg, ysB = h^T, global store
    {
      f32x4 aU = {0.f, 0.f, 0.f, 0.f}, aC = {0.f, 0.f, 0.f, 0.f};
#pragma unroll
      for (int kh = 0; kh < 7; ++kh) {
        bf16x8 a = fragL(zTB, m0, 232, kh * 32, lane);
        const u16* pu = uwcwB + (size_t)((0 * 4 + wc) * 7 + kh) * 512 + lane * 8;
        const u16* pc = uwcwB + (size_t)((1 * 4 + wc) * 7 + kh) * 512 + lane * 8;
        aU = MFMA(a, *(const bf16x8*)pu, aU);
        aC = MFMA(a, *(const bf16x8*)pc, aC);
      }
      int o = col;
      float bu_ = ub[o], bc_ = cb[o];
      float4 ov;
#pragma unroll
      for (int j = 0; j < 4; ++j) {
        int n = m0 + gq + j;
        float u = 1.f / (1.f + __expf(-(aU[j] + bu_)));
        float z = aC[j] + bc_;
        z = fminf(fmaxf(z, -15.f), 15.f);
        float e2 = __expf(2.f * z);
        float cval = (e2 - 1.f) / (e2 + 1.f);
        float hn = u * hdreg[j] + (1.f - u) * cval;
        hreg[j] = hn;
        (&ov.x)[j] = hn;
        ysB[n * 72 + o] = f2bf(hn);
      }
      if (useStage) {
        *(float4*)(wsOut + ((size_t)b * 96 + s) * 4096 + o * 64 + m0 + gq) = ov;
      } else {
#pragma unroll
        for (int j = 0; j < 4; ++j) {
          int n = m0 + gq + j;
          out[((size_t)(b * 64 + n) * 64 + o) * 96 + s] = (&ov.x)[j];
        }
      }
    }
    __syncthreads();
  }
}

// ws [b][s][d][n] -> out [b][n][d][s]
__global__ __launch_bounds__(256)
void transp_kernel(const float* __restrict__ ws, float* __restrict__ out) {
  int blk = blockIdx.x;
  int b = blk >> 6, o = blk & 63;
  __shared__ float t[96 * 68];
  for (int i = threadIdx.x; i < 96 * 64; i += 256) {
    int ss = i >> 6, n = i & 63;
    t[ss * 68 + n] = ws[((size_t)b * 96 + ss) * 4096 + o * 64 + n];
  }
  __syncthreads();
  for (int i = threadIdx.x; i < 64 * 96; i += 256) {
    int n = i / 96, ss = i - n * 96;
    out[((size_t)(b * 64 + n) * 64 + o) * 96 + ss] = t[ss * 68 + n];
  }
}

extern "C" void kernel_launch(void* const* d_in, const int* in_sizes, int n_in,
                              void* d_out, int out_size, void* d_ws, size_t ws_size,
                              hipStream_t stream)
{
  (void)in_sizes; (void)n_in; (void)out_size;
  const float* x     = (const float*)d_in[0];
  const float* adj   = (const float*)d_in[1];
  const float* h0    = (const float*)d_in[3];
  const float* t_inw = (const float*)d_in[4];
  const float* t_inb = (const float*)d_in[5];
  const float* t_ow  = (const float*)d_in[6];
  const float* t_ob  = (const float*)d_in[7];
  const float* t_w1  = (const float*)d_in[8];
  const float* t_b1  = (const float*)d_in[9];
  const float* t_w2  = (const float*)d_in[10];
  const float* t_b2  = (const float*)d_in[11];
  const float* t_g1  = (const float*)d_in[12];
  const float* t_be1 = (const float*)d_in[13];
  const float* t_g2  = (const float*)d_in[14];
  const float* t_be2 = (const float*)d_in[15];
  const float* uw    = (const float*)d_in[16];
  const float* ub    = (const float*)d_in[17];
  const float* cw    = (const float*)d_in[18];
  const float* cb    = (const float*)d_in[19];
  float* out = (float*)d_out;

  const size_t stageBytes = (size_t)128 * 96 * 4096 * 4;  // 201.3 MB
  const size_t wRegion = 131072;                          // 128 KB for weight frags
  int prew = 0, useStage = 0;
  size_t stageOff = 0;
  if (ws_size >= wRegion + stageBytes)      { prew = 1; useStage = 1; stageOff = wRegion; }
  else if (ws_size >= stageBytes)           { useStage = 1; }
  else if (ws_size >= wRegion)              { prew = 1; }

  u16* wsW = (u16*)d_ws;
  float* wsOut = (float*)((char*)d_ws + stageOff);

  if (prew)
    hipLaunchKernelGGL(prep_kernel, dim3(12), dim3(256), 0, stream,
                       t_inw, t_ow, t_w1, t_w2, wsW);

  if (prew)
    hipLaunchKernelGGL(gcrnn_kernel<1>, dim3(128), dim3(TPB), 0, stream,
                       x, adj, h0, t_inw, t_inb, t_ow, t_ob, t_w1, t_b1,
                       t_w2, t_b2, t_g1, t_be1, t_g2, t_be2, uw, ub, cw, cb,
                       wsW, wsOut, out, useStage);
  else
    hipLaunchKernelGGL(gcrnn_kernel<0>, dim3(128), dim3(TPB), 0, stream,
                       x, adj, h0, t_inw, t_inb, t_ow, t_ob, t_w1, t_b1,
                       t_w2, t_b2, t_g1, t_be1, t_g2, t_be2, uw, ub, cw, cb,
                       wsW, wsOut, out, useStage);

  if (useStage)
    hipLaunchKernelGGL(transp_kernel, dim3(128 * 64), dim3(256), 0, stream, wsOut, out);
}

// Round 5
// 1556.627 us; speedup vs baseline: 1.5412x; 1.5412x over previous
//
#include <hip/hip_runtime.h>
#include <math.h>

#define TPB 512

typedef __attribute__((ext_vector_type(8))) short bf16x8;
typedef __attribute__((ext_vector_type(4))) float f32x4;
typedef unsigned short u16;

#define MFMA(a, b, c) __builtin_amdgcn_mfma_f32_16x16x32_bf16(a, b, c, 0, 0, 0)

__device__ __forceinline__ u16 f2bf(float f) {
  union { float f; unsigned u; } v; v.f = f;
  unsigned u = v.u;
  return (u16)((u + 0x7fffu + ((u >> 16) & 1u)) >> 16);  // RNE
}
__device__ __forceinline__ float bf2f(u16 h) {
  union { unsigned u; float f; } v; v.u = ((unsigned)h) << 16; return v.f;
}

// fragment from LDS bf16 [row][pitch]: lane row = row0+(lane&15), k = kb+(lane>>4)*8+j
__device__ __forceinline__ bf16x8 fragL(const u16* B, int row0, int pitch, int kb, int lane) {
  return *(const bf16x8*)(B + (row0 + (lane & 15)) * pitch + kb + ((lane >> 4) << 3));
}
// fragment from global fp32 [row][stride] with on-the-fly bf16 convert (PREW=0 fallback)
__device__ __forceinline__ bf16x8 fragG(const float* __restrict__ W, int row0, int stride,
                                        int kb, int lane) {
  const float* p = W + (size_t)(row0 + (lane & 15)) * stride + kb + ((lane >> 4) << 3);
  float4 a = *(const float4*)p, b = *(const float4*)(p + 4);
  bf16x8 r;
  r[0] = (short)f2bf(a.x); r[1] = (short)f2bf(a.y); r[2] = (short)f2bf(a.z); r[3] = (short)f2bf(a.w);
  r[4] = (short)f2bf(b.x); r[5] = (short)f2bf(b.y); r[6] = (short)f2bf(b.z); r[7] = (short)f2bf(b.w);
  return r;
}
// encoder weight fragment: pre-swizzled bf16 in ws (PREW=1) or fp32 global (PREW=0)
template<int PREW>
__device__ __forceinline__ bf16x8 wfrag(const float* __restrict__ Wg,
                                        const u16* __restrict__ Wp,
                                        int m, int f, int kh, int lane) {
  if constexpr (PREW)
    return *(const bf16x8*)(Wp + (size_t)m * 4096 + f * 1024 + kh * 512 + lane * 8);
  else
    return fragG(Wg, f * 16, 64, kh * 32, lane);
}

// prep: pre-swizzle 12 encoder 64x64 matrices into bf16 fragment layout; block 12 = adj2 fp32
__global__ __launch_bounds__(256)
void prep_kernel(const float* __restrict__ t_inw, const float* __restrict__ t_ow,
                 const float* __restrict__ t_w1, const float* __restrict__ t_w2,
                 const float* __restrict__ adj, u16* __restrict__ wp) {
  int m = blockIdx.x;
  if (m == 12) {
    float* adj2 = (float*)(wp + 12 * 4096);
    for (int e = threadIdx.x; e < 4096; e += 256) {
      int w = e >> 6, u = e & 63;
      float sum = 0.f;
      for (int v = 0; v < 64; ++v) sum += adj[w * 64 + v] * adj[v * 64 + u];
      adj2[e] = sum;
    }
    return;
  }
  int l = m / 6, r = m % 6;
  const float* W;
  if (r < 3)       W = t_inw + l * 12288 + r * 4096;
  else if (r == 3) W = t_ow + l * 4096;
  else if (r == 4) W = t_w1 + l * 4096;
  else             W = t_w2 + l * 4096;
  for (int t = threadIdx.x; t < 4096; t += 256) {
    int j = t & 7, ln = (t >> 3) & 63, kh = (t >> 9) & 1, f = t >> 10;
    int row = f * 16 + (ln & 15);
    int k = kh * 32 + ((ln >> 4) << 3) + j;
    wp[(size_t)m * 4096 + t] = f2bf(W[row * 64 + k]);
  }
}

template<int PREW>
__global__ __launch_bounds__(TPB, 1)
void gcrnn_kernel(const float* __restrict__ x,      // (128,3,64,96)
                  const float* __restrict__ adj,    // (64,64)
                  const float* __restrict__ h0,     // (128,64,64)
                  const float* __restrict__ t_inw, const float* __restrict__ t_inb,
                  const float* __restrict__ t_ow,  const float* __restrict__ t_ob,
                  const float* __restrict__ t_w1,  const float* __restrict__ t_b1,
                  const float* __restrict__ t_w2,  const float* __restrict__ t_b2,
                  const float* __restrict__ t_g1,  const float* __restrict__ t_be1,
                  const float* __restrict__ t_g2,  const float* __restrict__ t_be2,
                  const float* __restrict__ uw,    const float* __restrict__ ub,
                  const float* __restrict__ cw,    const float* __restrict__ cb,
                  const u16* __restrict__ wsW,     // pre-swizzled encoder weights + adj2
                  float* __restrict__ wsOut,       // staging [b][s][d][n] (if useStage)
                  float* __restrict__ out,         // (128,64,64,96)
                  int useStage)
{
  const int b = blockIdx.x;
  const int tid = threadIdx.x;
  const int wv = tid >> 6;          // 0..7
  const int lane = tid & 63;
  const int lx = lane & 15;
  const int gq = (lane >> 4) << 2;  // 0,4,8,12
  const int rs = wv & 3;            // row stripe for owned tiles
  const int of0 = (wv >> 2) * 2;    // owned col-frag pair base {0,2}

  __shared__ __align__(16) u16 adjB[64 * 72];          //  9216 B adj[w][v]
  __shared__ __align__(16) u16 adj2B[64 * 72];         //  9216 B (adj@adj)[w][u]
  __shared__ __align__(16) u16 ysB[64 * 72];           //  9216 B y[n][d] / h^T
  __shared__ __align__(16) u16 pool[4 * 4608];         // 36864 B Qb|Kb|VTb|Pb ; xgB aliases
  __shared__ __align__(16) u16 zTB[64 * 232];          // 29696 B zT[n][c], c>=204 zero
  __shared__ __align__(16) u16 uwcwB[2 * 4 * 7 * 512]; // 57344 B conv weight frags
  // total 151552 B

  u16* Qb  = pool;
  u16* Kb  = pool + 4608;
  u16* VTb = pool + 9216;
  u16* Pb  = pool + 13824;
  u16* xgB = pool;          // 80 rows x 72 (rows 68..79 stale-finite, cols discarded)

  // ---- one-time init ----
  float hreg[2][4];         // h[o][n]: o=(of0+ff)*16+lx, n=rs*16+gq+j
  {
    const int nb = rs * 16 + gq;
#pragma unroll
    for (int ff = 0; ff < 2; ++ff) {
      int o = (of0 + ff) * 16 + lx;
      float4 hv = *(const float4*)(h0 + (size_t)b * 4096 + o * 64 + nb);
#pragma unroll
      for (int j = 0; j < 4; ++j) {
        hreg[ff][j] = (&hv.x)[j];
        ysB[(nb + j) * 72 + o] = f2bf(hreg[ff][j]);
      }
    }
  }
  for (int i = tid; i < 4096; i += TPB)
    adjB[(i >> 6) * 72 + (i & 63)] = f2bf(adj[i]);
  if constexpr (PREW) {
    const float* adj2g = (const float*)(wsW + 12 * 4096);
    for (int i = tid; i < 4096; i += TPB)
      adj2B[(i >> 6) * 72 + (i & 63)] = f2bf(adj2g[i]);
  } else {
    for (int i = tid; i < 4096; i += TPB) {
      int w = i >> 6, u = i & 63;
      float sum = 0.f;
      for (int v = 0; v < 64; ++v) sum += adj[w * 64 + v] * adj[v * 64 + u];
      adj2B[w * 72 + u] = f2bf(sum);
    }
  }
  for (int i = tid; i < 2 * 4 * 7 * 512; i += TPB) {
    int t = i;
    int j = t & 7; t >>= 3;
    int ln = t & 63; t >>= 6;
    int kh = t % 7; t /= 7;
    int f = t & 3; int mat = t >> 2;
    int o = f * 16 + (ln & 15);
    int k = kh * 32 + ((ln >> 4) << 3) + j;
    const float* W = mat ? cw : uw;
    uwcwB[i] = (k < 204) ? f2bf(W[o * 204 + k]) : (u16)0;
  }
  for (int i = tid; i < 64 * 28; i += TPB)
    zTB[(i / 28) * 232 + 204 + (i % 28)] = 0;
  __syncthreads();

  const float* times = x + ((size_t)b * 3 + 2) * 64 * 96;  // x[b,2,0,:]
  float hdreg[2][4];

  for (int s = 0; s < 96; ++s) {
    float dcur = (s == 0) ? 0.f : (times[s] - times[s - 1]);
    float sq1 = sqrtf(1.f - dcur), sq2 = sqrtf(dcur);

    // ---- two encoder layers (6 barriers each) ----
    for (int l = 0; l < 2; ++l) {
      const int l6 = l * 6;
      const float* inw = t_inw + l * 12288;
      const float* inb = t_inb + l * 192;
      const float* ow  = t_ow  + l * 4096;
      const float* ob  = t_ob  + l * 64;
      const float* w1  = t_w1  + l * 4096;
      const float* bb1 = t_b1  + l * 64;
      const float* w2  = t_w2  + l * 4096;
      const float* bb2 = t_b2  + l * 64;
      const float* g1  = t_g1  + l * 64;
      const float* be1 = t_be1 + l * 64;
      const float* g2  = t_g2  + l * 64;
      const float* be2 = t_be2 + l * 64;

      // A: Q,K (each wave: its rs-stripe, col-frags {wv>>2, wv>>2+2})
      {
        bf16x8 a0 = fragL(ysB, rs * 16, 72, 0, lane);
        bf16x8 a1 = fragL(ysB, rs * 16, 72, 32, lane);
#pragma unroll
        for (int qk = 0; qk < 2; ++qk) {
          u16* dst = qk ? Kb : Qb;
          const float* Wg = inw + qk * 4096;
#pragma unroll
          for (int fi = 0; fi < 2; ++fi) {
            int f = (wv >> 2) + fi * 2;
            f32x4 acc = {0.f, 0.f, 0.f, 0.f};
            acc = MFMA(a0, wfrag<PREW>(Wg, wsW, l6 + qk, f, 0, lane), acc);
            acc = MFMA(a1, wfrag<PREW>(Wg, wsW, l6 + qk, f, 1, lane), acc);
            int col = f * 16 + lx;
            float bv = inb[qk * 64 + col];
#pragma unroll
            for (int j = 0; j < 4; ++j)
              dst[(rs * 16 + gq + j) * 72 + col] = f2bf(acc[j] + bv);
          }
        }
      }
      __syncthreads();

      // B: waves 0-3: S row-stripe + wave-local softmax -> P; waves 4-7: V^T
      if (wv < 4) {
        bf16x8 qa0 = fragL(Qb, rs * 16, 72, 0, lane);
        bf16x8 qa1 = fragL(Qb, rs * 16, 72, 32, lane);
        f32x4 sc[4];
#pragma unroll
        for (int f = 0; f < 4; ++f) {
          f32x4 acc = {0.f, 0.f, 0.f, 0.f};
          acc = MFMA(qa0, fragL(Kb, f * 16, 72, 0, lane), acc);
          acc = MFMA(qa1, fragL(Kb, f * 16, 72, 32, lane), acc);
#pragma unroll
          for (int j = 0; j < 4; ++j) acc[j] *= 0.125f;
          sc[f] = acc;
        }
#pragma unroll
        for (int j = 0; j < 4; ++j) {
          float m1 = fmaxf(fmaxf(sc[0][j], sc[1][j]), fmaxf(sc[2][j], sc[3][j]));
          m1 = fmaxf(m1, __shfl_xor(m1, 1));
          m1 = fmaxf(m1, __shfl_xor(m1, 2));
          m1 = fmaxf(m1, __shfl_xor(m1, 4));
          m1 = fmaxf(m1, __shfl_xor(m1, 8));
          float s1 = 0.f;
#pragma unroll
          for (int f = 0; f < 4; ++f) { float e = __expf(sc[f][j] - m1); sc[f][j] = e; s1 += e; }
          s1 += __shfl_xor(s1, 1); s1 += __shfl_xor(s1, 2);
          s1 += __shfl_xor(s1, 4); s1 += __shfl_xor(s1, 8);
          float inv = 1.f / s1;
          int row = rs * 16 + gq + j;
#pragma unroll
          for (int f = 0; f < 4; ++f)
            Pb[row * 72 + f * 16 + lx] = f2bf(sc[f][j] * inv);
        }
      } else {
        bf16x8 wa0 = wfrag<PREW>(inw + 8192, wsW, l6 + 2, rs, 0, lane);
        bf16x8 wa1 = wfrag<PREW>(inw + 8192, wsW, l6 + 2, rs, 1, lane);
#pragma unroll
        for (int f = 0; f < 4; ++f) {
          f32x4 acc = {0.f, 0.f, 0.f, 0.f};
          acc = MFMA(wa0, fragL(ysB, f * 16, 72, 0, lane), acc);
          acc = MFMA(wa1, fragL(ysB, f * 16, 72, 32, lane), acc);
#pragma unroll
          for (int j = 0; j < 4; ++j) {
            int dd = rs * 16 + gq + j;
            VTb[dd * 72 + f * 16 + lx] = f2bf(acc[j] + inb[128 + dd]);
          }
        }
      }
      __syncthreads();

      // C: AO = P @ V -> Qb (2 tiles/wave)
      {
        bf16x8 pa0 = fragL(Pb, rs * 16, 72, 0, lane);
        bf16x8 pa1 = fragL(Pb, rs * 16, 72, 32, lane);
#pragma unroll
        for (int fi = 0; fi < 2; ++fi) {
          int f = (wv >> 2) + fi * 2;
          f32x4 acc = {0.f, 0.f, 0.f, 0.f};
          acc = MFMA(pa0, fragL(VTb, f * 16, 72, 0, lane), acc);
          acc = MFMA(pa1, fragL(VTb, f * 16, 72, 32, lane), acc);
#pragma unroll
          for (int j = 0; j < 4; ++j)
            Qb[(rs * 16 + gq + j) * 72 + f * 16 + lx] = f2bf(acc[j]);
        }
      }
      __syncthreads();

      // D: proj + residual + wave-local LN (waves 0-3, full row stripe)
      if (wv < 4) {
        bf16x8 a0 = fragL(Qb, rs * 16, 72, 0, lane);
        bf16x8 a1 = fragL(Qb, rs * 16, 72, 32, lane);
        float t4[4][4];
#pragma unroll
        for (int f = 0; f < 4; ++f) {
          f32x4 acc = {0.f, 0.f, 0.f, 0.f};
          acc = MFMA(a0, wfrag<PREW>(ow, wsW, l6 + 3, f, 0, lane), acc);
          acc = MFMA(a1, wfrag<PREW>(ow, wsW, l6 + 3, f, 1, lane), acc);
          int col = f * 16 + lx;
          float bv = ob[col];
#pragma unroll
          for (int j = 0; j < 4; ++j) {
            int row = rs * 16 + gq + j;
            t4[f][j] = acc[j] + bv + bf2f(ysB[row * 72 + col]);
          }
        }
#pragma unroll
        for (int j = 0; j < 4; ++j) {
          float s1 = t4[0][j] + t4[1][j] + t4[2][j] + t4[3][j];
          float s2 = t4[0][j] * t4[0][j] + t4[1][j] * t4[1][j]
                   + t4[2][j] * t4[2][j] + t4[3][j] * t4[3][j];
          s1 += __shfl_xor(s1, 1); s2 += __shfl_xor(s2, 1);
          s1 += __shfl_xor(s1, 2); s2 += __shfl_xor(s2, 2);
          s1 += __shfl_xor(s1, 4); s2 += __shfl_xor(s2, 4);
          s1 += __shfl_xor(s1, 8); s2 += __shfl_xor(s2, 8);
          float mu = s1 * 0.015625f;
          float rstd = rsqrtf(s2 * 0.015625f - mu * mu + 1e-5f);
          int row = rs * 16 + gq + j;
#pragma unroll
          for (int f = 0; f < 4; ++f) {
            int col = f * 16 + lx;
            ysB[row * 72 + col] = f2bf((t4[f][j] - mu) * rstd * g1[col] + be1[col]);
          }
        }
      }
      __syncthreads();

      // E: FF1 relu -> Kb (2 tiles/wave)
      {
        bf16x8 a0 = fragL(ysB, rs * 16, 72, 0, lane);
        bf16x8 a1 = fragL(ysB, rs * 16, 72, 32, lane);
#pragma unroll
        for (int fi = 0; fi < 2; ++fi) {
          int f = (wv >> 2) + fi * 2;
          f32x4 acc = {0.f, 0.f, 0.f, 0.f};
          acc = MFMA(a0, wfrag<PREW>(w1, wsW, l6 + 4, f, 0, lane), acc);
          acc = MFMA(a1, wfrag<PREW>(w1, wsW, l6 + 4, f, 1, lane), acc);
          int col = f * 16 + lx;
          float bv = bb1[col];
#pragma unroll
          for (int j = 0; j < 4; ++j)
            Kb[(rs * 16 + gq + j) * 72 + col] = f2bf(fmaxf(acc[j] + bv, 0.f));
        }
      }
      __syncthreads();

      // F: FF2 + residual + wave-local LN (waves 0-3)
      if (wv < 4) {
        bf16x8 a0 = fragL(Kb, rs * 16, 72, 0, lane);
        bf16x8 a1 = fragL(Kb, rs * 16, 72, 32, lane);
        float t4[4][4];
#pragma unroll
        for (int f = 0; f < 4; ++f) {
          f32x4 acc = {0.f, 0.f, 0.f, 0.f};
          acc = MFMA(a0, wfrag<PREW>(w2, wsW, l6 + 5, f, 0, lane), acc);
          acc = MFMA(a1, wfrag<PREW>(w2, wsW, l6 + 5, f, 1, lane), acc);
          int col = f * 16 + lx;
          float bv = bb2[col];
#pragma unroll
          for (int j = 0; j < 4; ++j) {
            int row = rs * 16 + gq + j;
            t4[f][j] = acc[j] + bv + bf2f(ysB[row * 72 + col]);
          }
        }
#pragma unroll
        for (int j = 0; j < 4; ++j) {
          float s1 = t4[0][j] + t4[1][j] + t4[2][j] + t4[3][j];
          float s2 = t4[0][j] * t4[0][j] + t4[1][j] * t4[1][j]
                   + t4[2][j] * t4[2][j] + t4[3][j] * t4[3][j];
          s1 += __shfl_xor(s1, 1); s2 += __shfl_xor(s2, 1);
          s1 += __shfl_xor(s1, 2); s2 += __shfl_xor(s2, 2);
          s1 += __shfl_xor(s1, 4); s2 += __shfl_xor(s2, 4);
          s1 += __shfl_xor(s1, 8); s2 += __shfl_xor(s2, 8);
          float mu = s1 * 0.015625f;
          float rstd = rsqrtf(s2 * 0.015625f - mu * mu + 1e-5f);
          int row = rs * 16 + gq + j;
#pragma unroll
          for (int f = 0; f < 4; ++f) {
            int col = f * 16 + lx;
            ysB[row * 72 + col] = f2bf((t4[f][j] - mu) * rstd * g2[col] + be2[col]);
          }
        }
      }
      __syncthreads();
    }

    // G: xg rows 0..67 (pool) + zT cols 0..67; hd from registers
    {
      for (int i = tid; i < 256; i += TPB) {
        int f = i >> 6, n = i & 63;
        float v = (f < 3) ? x[(((size_t)b * 3 + f) * 64 + n) * 96 + s] : dcur;
        xgB[f * 72 + n] = f2bf(v);
        zTB[n * 232 + f] = f2bf(v);
      }
      const int nb = rs * 16 + gq;
#pragma unroll
      for (int ff = 0; ff < 2; ++ff) {
        int o = (of0 + ff) * 16 + lx;
        short4 hd4;
#pragma unroll
        for (int j = 0; j < 4; ++j) {
          int n = nb + j;
          float eps = bf2f(ysB[n * 72 + o]);
          float hd = sq1 * hreg[ff][j] - sq2 * eps;
          hdreg[ff][j] = hd;
          u16 hb = f2bf(hd);
          ((u16*)&hd4)[j] = hb;
          zTB[n * 232 + 4 + o] = hb;
        }
        *(short4*)(xgB + (4 + o) * 72 + nb) = hd4;
      }
    }
    __syncthreads();

    // H: x1T (adj @ xg^T) and x2T (adj2 @ xg^T) -> zT[68..203], fused (5 tiles/wave)
    for (int t = wv; t < 40; t += 8) {
      int which = (t >= 20) ? 1 : 0;
      int tt = t - which * 20;
      int rw = tt & 3, cf = tt >> 2;
      const u16* A = which ? adj2B : adjB;
      f32x4 acc = {0.f, 0.f, 0.f, 0.f};
      acc = MFMA(fragL(A, rw * 16, 72, 0, lane), fragL(xgB, cf * 16, 72, 0, lane), acc);
      acc = MFMA(fragL(A, rw * 16, 72, 32, lane), fragL(xgB, cf * 16, 72, 32, lane), acc);
      int c = cf * 16 + lx;
      if (c < 68) {
#pragma unroll
        for (int j = 0; j < 4; ++j)
          zTB[(rw * 16 + gq + j) * 232 + 68 + which * 68 + c] = f2bf(acc[j]);
      }
    }
    __syncthreads();

    // J: conv (u,c) + gate -> hreg, ysB = h^T, emit
    {
      f32x4 aU[2] = {{0.f,0.f,0.f,0.f},{0.f,0.f,0.f,0.f}};
      f32x4 aC[2] = {{0.f,0.f,0.f,0.f},{0.f,0.f,0.f,0.f}};
#pragma unroll
      for (int kh = 0; kh < 7; ++kh) {
        bf16x8 a = fragL(zTB, rs * 16, 232, kh * 32, lane);
#pragma unroll
        for (int ff = 0; ff < 2; ++ff) {
          int f = of0 + ff;
          const u16* pu = uwcwB + (size_t)((0 * 4 + f) * 7 + kh) * 512 + lane * 8;
          const u16* pc = uwcwB + (size_t)((1 * 4 + f) * 7 + kh) * 512 + lane * 8;
          aU[ff] = MFMA(a, *(const bf16x8*)pu, aU[ff]);
          aC[ff] = MFMA(a, *(const bf16x8*)pc, aC[ff]);
        }
      }
      const int nb = rs * 16 + gq;
#pragma unroll
      for (int ff = 0; ff < 2; ++ff) {
        int o = (of0 + ff) * 16 + lx;
        float bu_ = ub[o], bc_ = cb[o];
        float4 ov;
#pragma unroll
        for (int j = 0; j < 4; ++j) {
          int n = nb + j;
          float u = 1.f / (1.f + __expf(-(aU[ff][j] + bu_)));
          float z = aC[ff][j] + bc_;
          z = fminf(fmaxf(z, -15.f), 15.f);
          float e2 = __expf(2.f * z);
          float cval = (e2 - 1.f) / (e2 + 1.f);
          float hn = u * hdreg[ff][j] + (1.f - u) * cval;
          hreg[ff][j] = hn;
          (&ov.x)[j] = hn;
          ysB[n * 72 + o] = f2bf(hn);
        }
        if (useStage) {
          *(float4*)(wsOut + ((size_t)b * 96 + s) * 4096 + o * 64 + nb) = ov;
        } else {
#pragma unroll
          for (int j = 0; j < 4; ++j)
            out[((size_t)(b * 64 + (nb + j)) * 64 + o) * 96 + s] = (&ov.x)[j];
        }
      }
    }
    __syncthreads();
  }
}

// ws [b][s][d][n] -> out [b][n][d][s]
__global__ __launch_bounds__(256)
void transp_kernel(const float* __restrict__ ws, float* __restrict__ out) {
  int blk = blockIdx.x;
  int b = blk >> 6, o = blk & 63;
  __shared__ float t[96 * 68];
  for (int i = threadIdx.x; i < 96 * 64; i += 256) {
    int ss = i >> 6, n = i & 63;
    t[ss * 68 + n] = ws[((size_t)b * 96 + ss) * 4096 + o * 64 + n];
  }
  __syncthreads();
  for (int i = threadIdx.x; i < 64 * 96; i += 256) {
    int n = i / 96, ss = i - n * 96;
    out[((size_t)(b * 64 + n) * 64 + o) * 96 + ss] = t[ss * 68 + n];
  }
}

extern "C" void kernel_launch(void* const* d_in, const int* in_sizes, int n_in,
                              void* d_out, int out_size, void* d_ws, size_t ws_size,
                              hipStream_t stream)
{
  (void)in_sizes; (void)n_in; (void)out_size;
  const float* x     = (const float*)d_in[0];
  const float* adj   = (const float*)d_in[1];
  const float* h0    = (const float*)d_in[3];
  const float* t_inw = (const float*)d_in[4];
  const float* t_inb = (const float*)d_in[5];
  const float* t_ow  = (const float*)d_in[6];
  const float* t_ob  = (const float*)d_in[7];
  const float* t_w1  = (const float*)d_in[8];
  const float* t_b1  = (const float*)d_in[9];
  const float* t_w2  = (const float*)d_in[10];
  const float* t_b2  = (const float*)d_in[11];
  const float* t_g1  = (const float*)d_in[12];
  const float* t_be1 = (const float*)d_in[13];
  const float* t_g2  = (const float*)d_in[14];
  const float* t_be2 = (const float*)d_in[15];
  const float* uw    = (const float*)d_in[16];
  const float* ub    = (const float*)d_in[17];
  const float* cw    = (const float*)d_in[18];
  const float* cb    = (const float*)d_in[19];
  float* out = (float*)d_out;

  const size_t stageBytes = (size_t)128 * 96 * 4096 * 4;   // 201.3 MB
  const size_t wRegion = 12 * 4096 * 2 + 4096 * 4;         // 114688 B (weights + adj2)
  int prew = 0, useStage = 0;
  size_t stageOff = 0;
  if (ws_size >= wRegion + stageBytes)      { prew = 1; useStage = 1; stageOff = wRegion; }
  else if (ws_size >= stageBytes)           { useStage = 1; }
  else if (ws_size >= wRegion)              { prew = 1; }

  u16* wsW = (u16*)d_ws;
  float* wsOut = (float*)((char*)d_ws + stageOff);

  if (prew)
    hipLaunchKernelGGL(prep_kernel, dim3(13), dim3(256), 0, stream,
                       t_inw, t_ow, t_w1, t_w2, adj, wsW);

  if (prew)
    hipLaunchKernelGGL(gcrnn_kernel<1>, dim3(128), dim3(TPB), 0, stream,
                       x, adj, h0, t_inw, t_inb, t_ow, t_ob, t_w1, t_b1,
                       t_w2, t_b2, t_g1, t_be1, t_g2, t_be2, uw, ub, cw, cb,
                       wsW, wsOut, out, useStage);
  else
    hipLaunchKernelGGL(gcrnn_kernel<0>, dim3(128), dim3(TPB), 0, stream,
                       x, adj, h0, t_inw, t_inb, t_ow, t_ob, t_w1, t_b1,
                       t_w2, t_b2, t_g1, t_be1, t_g2, t_be2, uw, ub, cw, cb,
                       wsW, wsOut, out, useStage);

  if (useStage)
    hipLaunchKernelGGL(transp_kernel, dim3(128 * 64), dim3(256), 0, stream, wsOut, out);
}